// Round 3
// baseline (76.416 us; speedup 1.0000x reference)
//
#include <hip/hip_runtime.h>

// EnvironmentSpecificDecoder — MI355X bf16-MFMA, round 3.
// B=32,T=64,d=128,L=64,H=256,H2=128,N_ENVS=8. out = [mu(262144) | sigma(262144)] fp32.
//
// Folding: h1 = relu( (A^T Z) @ (W_sig@W1e[e]) + (b_sig@W1e[e] + b1e[e]) )
// Per (b,t) block (256 thr = 4 waves, 4 blocks/CU):
//   mc: Hc = Wc^T(M=h') x Zc(N=d), contrib reduced in-lane (+2 shfl) -> s_cpart
//   m1: M1 = Zt(M=l) x At(N=i), stored to LDS M1buf[i][l]
//   m2: P  = Wsw1(M=h) x M1buf(N=d); m3 (@W2) fused in-lane (+2 shfl) -> direct store
// ALL weight fragments are per-lane global->reg 16B loads (L2-hot) — no LDS
// staging, 3 barriers total, LDS = Zt(16K) + Zcb/M1buf(16K) + s_cpart(2K).

typedef __attribute__((ext_vector_type(8))) short short8;   // 8 x bf16 (4 VGPR)
typedef __attribute__((ext_vector_type(4))) float f32x4;

#define MFMA16(a, b, c) __builtin_amdgcn_mfma_f32_16x16x32_bf16((a), (b), (c), 0, 0, 0)

__device__ __forceinline__ unsigned short f2bf(float f) {
  union { float f; unsigned u; } v; v.f = f;
  unsigned r = v.u + 0x7fffu + ((v.u >> 16) & 1u);  // RNE
  return (unsigned short)(r >> 16);
}

// ---------------- setup: fold weights, transpose, cast bf16 (plain layouts) ----------
__global__ void setup_k(const float* __restrict__ A, const float* __restrict__ W_sig,
                        const float* __restrict__ b_sig, const float* __restrict__ W1e,
                        const float* __restrict__ b1e, const float* __restrict__ Wc,
                        unsigned short* __restrict__ wsw1t, unsigned short* __restrict__ at,
                        unsigned short* __restrict__ wct, float* __restrict__ bias1) {
  int blk = blockIdx.x, tid = threadIdx.x;
  if (blk < 512) {                       // wsw1t[e][h][l] = sum_h1 W_sig[l,h1]*W1e[e,h1,h]
    int e = blk >> 6, l = blk & 63, h = tid;
    const float* w1 = W1e + e * 65536 + h;
    const float* ws = W_sig + l * 256;
    float acc = 0.f;
    #pragma unroll 8
    for (int h1 = 0; h1 < 256; ++h1) acc = fmaf(ws[h1], w1[h1 * 256], acc);
    wsw1t[(e * 256 + h) * 64 + l] = f2bf(acc);
  } else if (blk < 576) {                // at[i][j] = A[j][i]
    int idx = (blk - 512) * 256 + tid, i = idx >> 7, j = idx & 127;
    at[i * 128 + j] = f2bf(A[j * 128 + i]);
  } else if (blk < 608) {                // wct[h'][l] = Wc[l][h']
    int idx = (blk - 576) * 256 + tid, h = idx >> 6, l = idx & 63;
    wct[h * 64 + l] = f2bf(Wc[l * 128 + h]);
  } else {                               // bias1[e][h] = b_sig@W1e[e] + b1e[e]
    int e = blk - 608, h = tid;
    const float* w1 = W1e + e * 65536 + h;
    float acc = b1e[e * 256 + h];
    for (int h1 = 0; h1 < 256; ++h1) acc = fmaf(b_sig[h1], w1[h1 * 256], acc);
    bias1[e * 256 + h] = acc;
  }
}

// ---------------- main kernel ----------------
// LDS map (38912 B -> 4 blocks/CU):
//      0: Zt  [64 l][128 j] bf16, swz ((l>>2)^l)&7 <<4
//  16384: Zcb [128 d][64 l] bf16 -> M1buf [128 i][64 l], swz (row&7)<<4
//  36864: s_cpart [4 waves][128 d] f32
__global__ __launch_bounds__(256, 4) void dec_k(
    const float* __restrict__ zs, const float* __restrict__ zcr,
    const int* __restrict__ regime, const float* __restrict__ W2e,
    const float* __restrict__ b2e, const float* __restrict__ bc,
    const float* __restrict__ Wo, const float* __restrict__ bo,
    const unsigned short* __restrict__ wsw1t, const unsigned short* __restrict__ at,
    const unsigned short* __restrict__ wct, const float* __restrict__ bias1,
    float* __restrict__ out) {
  __shared__ __align__(16) char sm[38912];
  float* s_cpart = (float*)(sm + 36864);

  const int bt = ((blockIdx.x & 7) << 8) | (blockIdx.x >> 3);  // XCD swizzle
  const int tid = threadIdx.x;
  const int lane = tid & 63, wave = tid >> 6, lg = lane >> 4, l15 = lane & 15;
  int e = regime[bt >> 6]; if (e >= 8) e = 0;
  const float b2_0 = b2e[2 * e], b2_1 = b2e[2 * e + 1], bo0 = bo[0];

  const float* Z  = zs  + (size_t)bt * 8192;
  const float* Zc = zcr + (size_t)bt * 8192;

  // ---- P0: load Z/Zc, convert to bf16, write LDS tiles ----
  float4 zcv[8];
  #pragma unroll
  for (int k = 0; k < 8; ++k) {
    int g = k * 256 + tid, d = g >> 4, l0 = (g & 15) * 4;
    zcv[k] = *(const float4*)(Zc + d * 64 + l0);
  }
  float4 z0v[4], z1v[4];
  #pragma unroll
  for (int k = 0; k < 4; ++k) {
    int g = k * 256 + tid, j = (g >> 4) * 2, l0 = (g & 15) * 4;
    const float* p = Z + j * 64 + l0;
    z0v[k] = *(const float4*)p;
    z1v[k] = *(const float4*)(p + 64);
  }
  // prefetch mc A-fragments (Wct, global->reg) so they fly across the barrier
  short8 wfr[2][2];
  #pragma unroll
  for (int m = 0; m < 2; ++m) {
    int hr = (wave * 2 + m) * 16 + l15;
    #pragma unroll
    for (int ks = 0; ks < 2; ++ks)
      wfr[m][ks] = *(const short8*)(wct + hr * 64 + lg * 8 + ks * 32);
  }

  #pragma unroll
  for (int k = 0; k < 8; ++k) {           // Zcb[d][l], swz8(d)
    int g = k * 256 + tid, d = g >> 4, l0 = (g & 15) * 4;
    unsigned lo = (unsigned)f2bf(zcv[k].x) | ((unsigned)f2bf(zcv[k].y) << 16);
    unsigned hi = (unsigned)f2bf(zcv[k].z) | ((unsigned)f2bf(zcv[k].w) << 16);
    int a = (d * 128 + l0 * 2) ^ ((d & 7) << 4);
    *(unsigned long long*)(sm + 16384 + a) = ((unsigned long long)hi << 32) | lo;
  }
  #pragma unroll
  for (int k = 0; k < 4; ++k) {           // Zt[l][j] transpose, swzT(l)
    int g = k * 256 + tid, j = (g >> 4) * 2, l0 = (g & 15) * 4;
    float a0[4] = {z0v[k].x, z0v[k].y, z0v[k].z, z0v[k].w};
    float a1[4] = {z1v[k].x, z1v[k].y, z1v[k].z, z1v[k].w};
    #pragma unroll
    for (int i2 = 0; i2 < 4; ++i2) {
      int l = l0 + i2;
      unsigned v = (unsigned)f2bf(a0[i2]) | ((unsigned)f2bf(a1[i2]) << 16);
      int a = (l * 256 + j * 2) ^ ((((l >> 2) ^ l) & 7) << 4);
      *(unsigned*)(sm + a) = v;
    }
  }
  __syncthreads();   // sync1: Zt/Zcb ready

  // ---- prefetch m1 B-fragments (At, global->reg): consumed in P2 ----
  short8 abfr[2][4];
  #pragma unroll
  for (int m = 0; m < 2; ++m) {
    int ir = (wave * 2 + m) * 16 + l15;
    #pragma unroll
    for (int ks = 0; ks < 4; ++ks)
      abfr[m][ks] = *(const short8*)(at + ir * 128 + lg * 8 + ks * 32);
  }
  // bc/Wo fragments for mc epilogue
  float4 bcv[2], wov[2];
  #pragma unroll
  for (int m = 0; m < 2; ++m) {
    int hb = (wave * 2 + m) * 16 + lg * 4;
    bcv[m] = *(const float4*)(bc + hb);
    wov[m] = *(const float4*)(Wo + hb);
  }

  // ---- P1 mc: Hc = Wct(M=h') x Zcb(N=d); contrib partial in-lane ----
  float cp[8];
  #pragma unroll
  for (int dt = 0; dt < 8; ++dt) cp[dt] = 0.f;
  #pragma unroll
  for (int dt = 0; dt < 8; ++dt) {
    int brow = dt * 16 + l15;
    short8 bfr0 = *(const short8*)(sm + 16384 + ((brow * 128 + lg * 16) ^ ((brow & 7) << 4)));
    short8 bfr1 = *(const short8*)(sm + 16384 + ((brow * 128 + lg * 16 + 64) ^ ((brow & 7) << 4)));
    #pragma unroll
    for (int m = 0; m < 2; ++m) {
      f32x4 acc = (f32x4){0.f, 0.f, 0.f, 0.f};
      acc = MFMA16(wfr[m][0], bfr0, acc);
      acc = MFMA16(wfr[m][1], bfr1, acc);
      #pragma unroll
      for (int r = 0; r < 4; ++r)
        cp[dt] += fmaxf(acc[r] + bcv[m][r], 0.f) * wov[m][r];
    }
  }
  #pragma unroll
  for (int dt = 0; dt < 8; ++dt) {
    cp[dt] += __shfl_xor(cp[dt], 16);
    cp[dt] += __shfl_xor(cp[dt], 32);
  }
  if (lane < 16) {
    #pragma unroll
    for (int dt = 0; dt < 8; ++dt)
      s_cpart[wave * 128 + dt * 16 + lane] = cp[dt];
  }

  // ---- P2 m1: M1 = Zt(M=l) x At(N=i) ----
  f32x4 acc1[4][2];
  #pragma unroll
  for (int lt = 0; lt < 4; ++lt)
    #pragma unroll
    for (int m = 0; m < 2; ++m) acc1[lt][m] = (f32x4){0.f, 0.f, 0.f, 0.f};
  #pragma unroll
  for (int ks = 0; ks < 4; ++ks) {
    #pragma unroll
    for (int lt = 0; lt < 4; ++lt) {
      int arow = lt * 16 + l15;
      short8 afr = *(const short8*)(sm + ((arow * 256 + lg * 16 + ks * 64) ^
                                          ((((arow >> 2) ^ arow) & 7) << 4)));
      #pragma unroll
      for (int m = 0; m < 2; ++m) acc1[lt][m] = MFMA16(afr, abfr[m][ks], acc1[lt][m]);
    }
  }
  __syncthreads();   // sync2: all Zcb reads retired (M1buf overwrites region)

  #pragma unroll
  for (int lt = 0; lt < 4; ++lt) {
    int l0 = lt * 16 + lg * 4;
    #pragma unroll
    for (int m = 0; m < 2; ++m) {
      int i = (wave * 2 + m) * 16 + l15;
      unsigned lo = (unsigned)f2bf(acc1[lt][m][0]) | ((unsigned)f2bf(acc1[lt][m][1]) << 16);
      unsigned hi = (unsigned)f2bf(acc1[lt][m][2]) | ((unsigned)f2bf(acc1[lt][m][3]) << 16);
      int a = (i * 128 + l0 * 2) ^ ((i & 7) << 4);
      *(unsigned long long*)(sm + 16384 + a) = ((unsigned long long)hi << 32) | lo;
    }
  }
  __syncthreads();   // sync3: M1buf ready

  // ---- P3 m2+m3: P = Wsw1(M=h) x M1buf(N=d); @W2 fused in-lane ----
  short8 mbfr[2][2];
  #pragma unroll
  for (int m = 0; m < 2; ++m) {
    int brow = (wave * 2 + m) * 16 + l15;
    #pragma unroll
    for (int ks = 0; ks < 2; ++ks)
      mbfr[m][ks] = *(const short8*)(sm + 16384 +
                       ((brow * 128 + lg * 16 + ks * 64) ^ ((brow & 7) << 4)));
  }
  float v0[2] = {0.f, 0.f}, v1[2] = {0.f, 0.f};
  const unsigned short* wse = wsw1t + (size_t)e * 16384;
  const float* b1e_ = bias1 + e * 256;
  const float* w2e_ = W2e + e * 512;
  #pragma unroll
  for (int ht = 0; ht < 16; ++ht) {
    int arow = ht * 16 + l15, h4 = ht * 16 + lg * 4;
    short8 wa0 = *(const short8*)(wse + arow * 64 + lg * 8);
    short8 wa1 = *(const short8*)(wse + arow * 64 + lg * 8 + 32);
    float4 b1v = *(const float4*)(b1e_ + h4);
    float4 w2a = *(const float4*)(w2e_ + h4 * 2);
    float4 w2b = *(const float4*)(w2e_ + h4 * 2 + 4);
    #pragma unroll
    for (int m = 0; m < 2; ++m) {
      f32x4 acc = (f32x4){0.f, 0.f, 0.f, 0.f};
      acc = MFMA16(wa0, mbfr[m][0], acc);
      acc = MFMA16(wa1, mbfr[m][1], acc);
      float p0 = fmaxf(acc[0] + b1v.x, 0.f), p1 = fmaxf(acc[1] + b1v.y, 0.f);
      float p2 = fmaxf(acc[2] + b1v.z, 0.f), p3 = fmaxf(acc[3] + b1v.w, 0.f);
      v0[m] = fmaf(p0, w2a.x, fmaf(p1, w2a.z, fmaf(p2, w2b.x, fmaf(p3, w2b.z, v0[m]))));
      v1[m] = fmaf(p0, w2a.y, fmaf(p1, w2a.w, fmaf(p2, w2b.y, fmaf(p3, w2b.w, v1[m]))));
    }
  }
  #pragma unroll
  for (int m = 0; m < 2; ++m) {
    v0[m] += __shfl_xor(v0[m], 16); v0[m] += __shfl_xor(v0[m], 32);
    v1[m] += __shfl_xor(v1[m], 16); v1[m] += __shfl_xor(v1[m], 32);
  }
  if (lane < 16) {
    #pragma unroll
    for (int m = 0; m < 2; ++m) {
      int d = (wave * 2 + m) * 16 + lane;
      float contrib = s_cpart[d] + s_cpart[128 + d] + s_cpart[256 + d] + s_cpart[384 + d];
      float mu = v0[m] + b2_0 + bo0 + contrib;
      float x = v1[m] + b2_1;
      float sg = fmaxf(x, 0.f) + log1pf(expf(-fabsf(x))) + 0.01f;
      out[(size_t)bt * 128 + d] = mu;
      out[262144 + (size_t)bt * 128 + d] = sg;
    }
  }
}

extern "C" void kernel_launch(void* const* d_in, const int* in_sizes, int n_in,
                              void* d_out, int out_size, void* d_ws, size_t ws_size,
                              hipStream_t stream) {
  const float* zs    = (const float*)d_in[0];
  const float* zcr   = (const float*)d_in[1];
  const float* A     = (const float*)d_in[2];
  const int*   reg   = (const int*)d_in[3];
  const float* W_sig = (const float*)d_in[4];
  const float* b_sig = (const float*)d_in[5];
  const float* W1e   = (const float*)d_in[6];
  const float* b1e   = (const float*)d_in[7];
  const float* W2e   = (const float*)d_in[8];
  const float* b2e   = (const float*)d_in[9];
  const float* Wc    = (const float*)d_in[10];
  const float* bcp   = (const float*)d_in[11];
  const float* Wo    = (const float*)d_in[12];
  const float* bo    = (const float*)d_in[13];

  unsigned short* wsw1t = (unsigned short*)d_ws;            // 8*256*64 bf16 = 256 KB
  unsigned short* at    = wsw1t + 131072;                   // 128*128 bf16  = 32 KB
  unsigned short* wct   = at + 16384;                       // 128*64 bf16   = 16 KB
  float* bias1          = (float*)(wct + 8192);             // 8*256 f32     = 8 KB

  setup_k<<<616, 256, 0, stream>>>(A, W_sig, b_sig, W1e, b1e, Wc, wsw1t, at, wct, bias1);
  dec_k<<<2048, 256, 0, stream>>>(zs, zcr, reg, W2e, b2e, bcp, Wo, bo,
                                  wsw1t, at, wct, bias1, (float*)d_out);
}

// Round 4
// 58.418 us; speedup vs baseline: 1.3081x; 1.3081x over previous
//
#include <hip/hip_runtime.h>

// EnvironmentSpecificDecoder — MI355X bf16-MFMA, round 4.
// B=32,T=64,d=128,L=64,H=256,H2=128,N_ENVS=8. out = [mu(262144) | sigma(262144)] fp32.
//
// Per (b,t) block (256 thr = 4 waves, 3 blocks/CU):
//   P0: Z/Zc fp32->bf16 -> LDS (Zt transposed, Zcb); async gload Wsw1-c0 + bw.
//   P1 mc: Hc = Wct(M=h') x Zcb(N=d); contrib in-lane (+2 shfl) -> s_cpart.
//   P2 m1: M1 = Zt(M=l) x At(N=i)  [At frags: fragment-major coalesced global].
//   sync2; issue Wsw1-c1 gload into dead Zt region; write M1buf (wave-private).
//   P3 m2+m3: P = Wsw1(M=h) x M1buf(N=d), @W2 fused in-lane (+2 shfl) -> store.
// Wsw1 chunks pre-swizzled in d_ws (granule g -> g^(row&7)) for linear gload_lds.

typedef __attribute__((ext_vector_type(8))) short short8;   // 8 x bf16 (4 VGPR)
typedef __attribute__((ext_vector_type(4))) float f32x4;

#define MFMA16(a, b, c) __builtin_amdgcn_mfma_f32_16x16x32_bf16((a), (b), (c), 0, 0, 0)

__device__ __forceinline__ unsigned short f2bf(float f) {
  union { float f; unsigned u; } v; v.f = f;
  unsigned r = v.u + 0x7fffu + ((v.u >> 16) & 1u);  // RNE
  return (unsigned short)(r >> 16);
}

__device__ __forceinline__ void gload16(const void* gsrc, void* ldsdst) {
  __builtin_amdgcn_global_load_lds(
      (const __attribute__((address_space(1))) unsigned int*)gsrc,
      (__attribute__((address_space(3))) unsigned int*)ldsdst, 16, 0, 0);
}

// ---------------- setup: fold/cast/repack weights (runs every launch) ----------------
// blocks 0..511   : wsw1s[e][c][hh][l] pre-swizzled (granule gl -> gl^(hh&7))
// blocks 512..575 : at_f fragment-major  [it(8)][ks(4)][lane(64)][e8(8)]
// blocks 576..607 : wct_f fragment-major [ht(8)][ks(2)][lane(64)][e8(8)]
// blocks 608..623 : bw[e][256..767] = W2e[e] copy
// blocks 624..631 : bw[e][0..255]   = b_sig@W1e[e] + b1e[e]
__global__ void setup_k(const float* __restrict__ A, const float* __restrict__ W_sig,
                        const float* __restrict__ b_sig, const float* __restrict__ W1e,
                        const float* __restrict__ b1e, const float* __restrict__ W2e,
                        const float* __restrict__ Wc,
                        unsigned short* __restrict__ wsw1s, unsigned short* __restrict__ at_f,
                        unsigned short* __restrict__ wct_f, float* __restrict__ bw) {
  int blk = blockIdx.x, tid = threadIdx.x;
  if (blk < 512) {                       // Wsw1[l][h] = sum_h1 W_sig[l,h1]*W1e[e,h1,h]
    int e = blk >> 6, l = blk & 63, h = tid;
    const float* w1 = W1e + e * 65536 + h;
    const float* ws = W_sig + l * 256;
    float acc = 0.f;
    #pragma unroll 8
    for (int h1 = 0; h1 < 256; ++h1) acc = fmaf(ws[h1], w1[h1 * 256], acc);
    int c = h >> 7, hh = h & 127, gl = l >> 3, e8 = l & 7;
    wsw1s[((e * 2 + c) * 128 + hh) * 64 + ((gl ^ (hh & 7)) << 3) + e8] = f2bf(acc);
  } else if (blk < 576) {                // at_f: value = A[j][i]
    int idx = (blk - 512) * 256 + tid;
    int frag = idx >> 3, e8 = idx & 7;
    int it = frag >> 8, ks = (frag >> 6) & 3, lane = frag & 63;
    int j = ks * 32 + (lane >> 4) * 8 + e8, i = it * 16 + (lane & 15);
    at_f[idx] = f2bf(A[j * 128 + i]);
  } else if (blk < 608) {                // wct_f: value = Wc[l][h']
    int idx = (blk - 576) * 256 + tid;
    int frag = idx >> 3, e8 = idx & 7;
    int ht = frag >> 7, ks = (frag >> 6) & 1, lane = frag & 63;
    int l = ks * 32 + (lane >> 4) * 8 + e8, h = ht * 16 + (lane & 15);
    wct_f[idx] = f2bf(Wc[l * 128 + h]);
  } else if (blk < 624) {                // bw W2 copy
    int idx = (blk - 608) * 256 + tid;   // 0..4095
    int e = idx >> 9, r = idx & 511;
    bw[e * 768 + 256 + r] = W2e[idx];
  } else {                               // bw bias fold
    int e = blk - 624, h = tid;
    const float* w1 = W1e + e * 65536 + h;
    float acc = b1e[e * 256 + h];
    for (int h1 = 0; h1 < 256; ++h1) acc = fmaf(b_sig[h1], w1[h1 * 256], acc);
    bw[e * 768 + h] = acc;
  }
}

// ---------------- main kernel ----------------
// LDS map (54272 B -> 3 blocks/CU):
//      0: Zt [64 l][128 j] bf16 swzT(l)   -> later Wsw1 chunk1 [128 hh][64 l] swz8
//  16384: Zcb [128 d][64 l] swz8          -> later M1buf [128 i][64 l] swz8 (wave-private)
//  32768: Wsw1 chunk0 [128 hh][64 l] swz8 (async gload from start)
//  49152: bw: bias1 256f | W2 512f        (async gload from start)
//  52224: s_cpart [4][128] f32
__global__ __launch_bounds__(256, 3) void dec_k(
    const float* __restrict__ zs, const float* __restrict__ zcr,
    const int* __restrict__ regime, const float* __restrict__ b2e,
    const float* __restrict__ bc, const float* __restrict__ Wo,
    const float* __restrict__ bo,
    const unsigned short* __restrict__ wsw1s, const unsigned short* __restrict__ at_f,
    const unsigned short* __restrict__ wct_f, const float* __restrict__ bw,
    float* __restrict__ out) {
  __shared__ __align__(16) char sm[54272];
  float* s_bias1 = (float*)(sm + 49152);
  float* s_W2    = s_bias1 + 256;
  float* s_cpart = (float*)(sm + 52224);

  const int bt = ((blockIdx.x & 7) << 8) | (blockIdx.x >> 3);  // XCD swizzle
  const int tid = threadIdx.x;
  const int lane = tid & 63, wave = tid >> 6, lg = lane >> 4, l15 = lane & 15;
  int e = regime[bt >> 6]; if (e >= 8) e = 0;
  const float b2_0 = b2e[2 * e], b2_1 = b2e[2 * e + 1], bo0 = bo[0];

  const float* Z  = zs  + (size_t)bt * 8192;
  const float* Zc = zcr + (size_t)bt * 8192;
  const unsigned short* wse = wsw1s + (size_t)e * 16384;

  // ---- issue async staging: Wsw1 chunk0 -> 32768, bw -> 49152 ----
  #pragma unroll
  for (int k = 0; k < 4; ++k)
    gload16((const char*)wse + (k * 256 + tid) * 16,
            sm + 32768 + (k * 256 + wave * 64) * 16);
  if (wave < 3)
    gload16((const char*)(bw + e * 768) + tid * 16, sm + 49152 + wave * 1024);

  // ---- P0: load Z/Zc, convert, write LDS tiles ----
  float4 zcv[8];
  #pragma unroll
  for (int k = 0; k < 8; ++k) {
    int g = k * 256 + tid, d = g >> 4, l0 = (g & 15) * 4;
    zcv[k] = *(const float4*)(Zc + d * 64 + l0);
  }
  float4 z0v[4], z1v[4];
  #pragma unroll
  for (int k = 0; k < 4; ++k) {
    int g = k * 256 + tid, j = (g >> 4) * 2, l0 = (g & 15) * 4;
    const float* p = Z + j * 64 + l0;
    z0v[k] = *(const float4*)p;
    z1v[k] = *(const float4*)(p + 64);
  }
  // mc A-fragments: fragment-major coalesced (1KB contiguous per wave-load)
  short8 wfr[2][2];
  #pragma unroll
  for (int m = 0; m < 2; ++m)
    #pragma unroll
    for (int ks = 0; ks < 2; ++ks)
      wfr[m][ks] = *(const short8*)(wct_f + ((((wave * 2 + m) * 2 + ks) * 64 + lane) << 3));

  #pragma unroll
  for (int k = 0; k < 8; ++k) {           // Zcb[d][l], swz8(d)
    int g = k * 256 + tid, d = g >> 4, l0 = (g & 15) * 4;
    unsigned lo = (unsigned)f2bf(zcv[k].x) | ((unsigned)f2bf(zcv[k].y) << 16);
    unsigned hi = (unsigned)f2bf(zcv[k].z) | ((unsigned)f2bf(zcv[k].w) << 16);
    int a = (d * 128 + l0 * 2) ^ ((d & 7) << 4);
    *(unsigned long long*)(sm + 16384 + a) = ((unsigned long long)hi << 32) | lo;
  }
  #pragma unroll
  for (int k = 0; k < 4; ++k) {           // Zt[l][j] transpose, swzT(l)
    int g = k * 256 + tid, j = (g >> 4) * 2, l0 = (g & 15) * 4;
    float a0[4] = {z0v[k].x, z0v[k].y, z0v[k].z, z0v[k].w};
    float a1[4] = {z1v[k].x, z1v[k].y, z1v[k].z, z1v[k].w};
    #pragma unroll
    for (int i2 = 0; i2 < 4; ++i2) {
      int l = l0 + i2;
      unsigned v = (unsigned)f2bf(a0[i2]) | ((unsigned)f2bf(a1[i2]) << 16);
      int a = (l * 256 + j * 2) ^ ((((l >> 2) ^ l) & 7) << 4);
      *(unsigned*)(sm + a) = v;
    }
  }
  __syncthreads();   // sync1: Zt/Zcb + chunk0 + bw ready

  // ---- m1 B-fragments (At, fragment-major coalesced) ----
  short8 abfr[2][4];
  #pragma unroll
  for (int m = 0; m < 2; ++m)
    #pragma unroll
    for (int ks = 0; ks < 4; ++ks)
      abfr[m][ks] = *(const short8*)(at_f + ((((wave * 2 + m) * 4 + ks) * 64 + lane) << 3));
  float4 bcv[2], wov[2];
  #pragma unroll
  for (int m = 0; m < 2; ++m) {
    int hb = (wave * 2 + m) * 16 + lg * 4;
    bcv[m] = *(const float4*)(bc + hb);
    wov[m] = *(const float4*)(Wo + hb);
  }

  // ---- P1 mc: Hc = Wct(M=h') x Zcb(N=d) ----
  float cp[8];
  #pragma unroll
  for (int dt = 0; dt < 8; ++dt) cp[dt] = 0.f;
  #pragma unroll
  for (int dt = 0; dt < 8; ++dt) {
    int brow = dt * 16 + l15;
    short8 bfr0 = *(const short8*)(sm + 16384 + ((brow * 128 + lg * 16) ^ ((brow & 7) << 4)));
    short8 bfr1 = *(const short8*)(sm + 16384 + ((brow * 128 + lg * 16 + 64) ^ ((brow & 7) << 4)));
    #pragma unroll
    for (int m = 0; m < 2; ++m) {
      f32x4 acc = (f32x4){0.f, 0.f, 0.f, 0.f};
      acc = MFMA16(wfr[m][0], bfr0, acc);
      acc = MFMA16(wfr[m][1], bfr1, acc);
      #pragma unroll
      for (int r = 0; r < 4; ++r)
        cp[dt] += fmaxf(acc[r] + bcv[m][r], 0.f) * wov[m][r];
    }
  }
  #pragma unroll
  for (int dt = 0; dt < 8; ++dt) {
    cp[dt] += __shfl_xor(cp[dt], 16);
    cp[dt] += __shfl_xor(cp[dt], 32);
  }
  if (lane < 16) {
    #pragma unroll
    for (int dt = 0; dt < 8; ++dt)
      s_cpart[wave * 128 + dt * 16 + lane] = cp[dt];
  }

  // ---- P2 m1: M1 = Zt(M=l) x At(N=i) ----
  f32x4 acc1[4][2];
  #pragma unroll
  for (int lt = 0; lt < 4; ++lt)
    #pragma unroll
    for (int m = 0; m < 2; ++m) acc1[lt][m] = (f32x4){0.f, 0.f, 0.f, 0.f};
  #pragma unroll
  for (int ks = 0; ks < 4; ++ks) {
    #pragma unroll
    for (int lt = 0; lt < 4; ++lt) {
      int arow = lt * 16 + l15;
      short8 afr = *(const short8*)(sm + ((arow * 256 + lg * 16 + ks * 64) ^
                                          ((((arow >> 2) ^ arow) & 7) << 4)));
      #pragma unroll
      for (int m = 0; m < 2; ++m) acc1[lt][m] = MFMA16(afr, abfr[m][ks], acc1[lt][m]);
    }
  }
  __syncthreads();   // sync2: Zcb/Zt reads retired; s_cpart visible

  // ---- issue Wsw1 chunk1 -> region 0 (dead Zt); flies during M1 write + P3-c0 ----
  #pragma unroll
  for (int k = 0; k < 4; ++k)
    gload16((const char*)wse + 16384 + (k * 256 + tid) * 16,
            sm + (k * 256 + wave * 64) * 16);

  // ---- M1buf write (wave-private rows -> no barrier before own-wave read) ----
  #pragma unroll
  for (int lt = 0; lt < 4; ++lt) {
    int l0 = lt * 16 + lg * 4;
    #pragma unroll
    for (int m = 0; m < 2; ++m) {
      int i = (wave * 2 + m) * 16 + l15;
      unsigned lo = (unsigned)f2bf(acc1[lt][m][0]) | ((unsigned)f2bf(acc1[lt][m][1]) << 16);
      unsigned hi = (unsigned)f2bf(acc1[lt][m][2]) | ((unsigned)f2bf(acc1[lt][m][3]) << 16);
      int a = (i * 128 + l0 * 2) ^ ((i & 7) << 4);
      *(unsigned long long*)(sm + 16384 + a) = ((unsigned long long)hi << 32) | lo;
    }
  }
  short8 mbfr[2][2];
  #pragma unroll
  for (int m = 0; m < 2; ++m) {
    int brow = (wave * 2 + m) * 16 + l15;
    #pragma unroll
    for (int ks = 0; ks < 2; ++ks)
      mbfr[m][ks] = *(const short8*)(sm + 16384 +
                       ((brow * 128 + lg * 16 + ks * 64) ^ ((brow & 7) << 4)));
  }

  // ---- P3: P = Wsw1(M=h) x M1buf(N=d); @W2 fused. c=0 from 32768, c=1 from 0 ----
  float v0[2] = {0.f, 0.f}, v1[2] = {0.f, 0.f};
  #pragma unroll
  for (int c = 0; c < 2; ++c) {
    if (c == 1) __syncthreads();   // sync3: chunk1 landed
    const char* wbase = (const char*)sm + (c == 0 ? 32768 : 0);
    #pragma unroll
    for (int ht = 0; ht < 8; ++ht) {
      int arow = ht * 16 + l15;                 // row within chunk
      int h4 = c * 128 + ht * 16 + lg * 4;      // absolute h for bias/W2
      short8 wa0 = *(const short8*)(wbase + ((arow * 128 + lg * 16) ^ ((arow & 7) << 4)));
      short8 wa1 = *(const short8*)(wbase + ((arow * 128 + lg * 16 + 64) ^ ((arow & 7) << 4)));
      float4 b1v = *(const float4*)(s_bias1 + h4);
      float4 w2a = *(const float4*)(s_W2 + h4 * 2);
      float4 w2b = *(const float4*)(s_W2 + h4 * 2 + 4);
      #pragma unroll
      for (int m = 0; m < 2; ++m) {
        f32x4 acc = (f32x4){0.f, 0.f, 0.f, 0.f};
        acc = MFMA16(wa0, mbfr[m][0], acc);
        acc = MFMA16(wa1, mbfr[m][1], acc);
        float p0 = fmaxf(acc[0] + b1v.x, 0.f), p1 = fmaxf(acc[1] + b1v.y, 0.f);
        float p2 = fmaxf(acc[2] + b1v.z, 0.f), p3 = fmaxf(acc[3] + b1v.w, 0.f);
        v0[m] = fmaf(p0, w2a.x, fmaf(p1, w2a.z, fmaf(p2, w2b.x, fmaf(p3, w2b.z, v0[m]))));
        v1[m] = fmaf(p0, w2a.y, fmaf(p1, w2a.w, fmaf(p2, w2b.y, fmaf(p3, w2b.w, v1[m]))));
      }
    }
  }
  #pragma unroll
  for (int m = 0; m < 2; ++m) {
    v0[m] += __shfl_xor(v0[m], 16); v0[m] += __shfl_xor(v0[m], 32);
    v1[m] += __shfl_xor(v1[m], 16); v1[m] += __shfl_xor(v1[m], 32);
  }
  if (lane < 16) {
    #pragma unroll
    for (int m = 0; m < 2; ++m) {
      int d = (wave * 2 + m) * 16 + lane;
      float contrib = s_cpart[d] + s_cpart[128 + d] + s_cpart[256 + d] + s_cpart[384 + d];
      float mu = v0[m] + b2_0 + bo0 + contrib;
      float x = v1[m] + b2_1;
      float sg = fmaxf(x, 0.f) + log1pf(expf(-fabsf(x))) + 0.01f;
      out[(size_t)bt * 128 + d] = mu;
      out[262144 + (size_t)bt * 128 + d] = sg;
    }
  }
}

extern "C" void kernel_launch(void* const* d_in, const int* in_sizes, int n_in,
                              void* d_out, int out_size, void* d_ws, size_t ws_size,
                              hipStream_t stream) {
  const float* zs    = (const float*)d_in[0];
  const float* zcr   = (const float*)d_in[1];
  const float* A     = (const float*)d_in[2];
  const int*   reg   = (const int*)d_in[3];
  const float* W_sig = (const float*)d_in[4];
  const float* b_sig = (const float*)d_in[5];
  const float* W1e   = (const float*)d_in[6];
  const float* b1e   = (const float*)d_in[7];
  const float* W2e   = (const float*)d_in[8];
  const float* b2e   = (const float*)d_in[9];
  const float* Wc    = (const float*)d_in[10];
  const float* bcp   = (const float*)d_in[11];
  const float* Wo    = (const float*)d_in[12];
  const float* bo    = (const float*)d_in[13];

  unsigned short* wsw1s = (unsigned short*)d_ws;            // 8*2*128*64 bf16 = 256 KB
  unsigned short* at_f  = wsw1s + 131072;                   // 16384 bf16 = 32 KB
  unsigned short* wct_f = at_f + 16384;                     // 8192 bf16  = 16 KB
  float* bw             = (float*)(wct_f + 8192);           // 8*768 f32  = 24 KB

  setup_k<<<632, 256, 0, stream>>>(A, W_sig, b_sig, W1e, b1e, W2e, Wc,
                                   wsw1s, at_f, wct_f, bw);
  dec_k<<<2048, 256, 0, stream>>>(zs, zcr, reg, b2e, bcp, Wo, bo,
                                  wsw1s, at_f, wct_f, bw, (float*)d_out);
}

// Round 5
// 51.960 us; speedup vs baseline: 1.4707x; 1.1243x over previous
//
#include <hip/hip_runtime.h>
#include <hip/hip_bf16.h>

// EnvironmentSpecificDecoder — MI355X bf16-MFMA, round 5.
// B=32,T=64,d=128,L=64,H=256,H2=128,N_ENVS=8. out = [mu(262144) | sigma(262144)] fp32.
//
// Per (b,t) block (256 thr = 4 waves, 4 blocks/CU, 2 barriers):
//   P0: Z/Zc fp32->bf16 (v_cvt_pk via __float22bfloat162_rn) -> LDS; gload bw.
//   P1 mc: Hc = Wct(M=h') x Zcb(N=d); contrib in-lane (+2 shfl) -> s_cpart.
//   P2 m1: M1 = Zt(M=l) x At(N=i)   [At/Wct/Wsw1 frags: fragment-major global->reg].
//   sync2; write M1buf (wave-private band); P3 m2+m3 with Wsw1 from registers.

typedef __attribute__((ext_vector_type(8))) short short8;   // 8 x bf16 (4 VGPR)
typedef __attribute__((ext_vector_type(4))) float f32x4;

#define MFMA16(a, b, c) __builtin_amdgcn_mfma_f32_16x16x32_bf16((a), (b), (c), 0, 0, 0)

__device__ __forceinline__ unsigned short f2bf(float f) {   // setup-side only
  union { float f; unsigned u; } v; v.f = f;
  unsigned r = v.u + 0x7fffu + ((v.u >> 16) & 1u);  // RNE
  return (unsigned short)(r >> 16);
}

__device__ __forceinline__ unsigned pkbf(float a, float b) {  // v_cvt_pk_bf16_f32
  __hip_bfloat162 t = __float22bfloat162_rn(float2{a, b});
  unsigned u; __builtin_memcpy(&u, &t, 4); return u;
}

__device__ __forceinline__ void gload16(const void* gsrc, void* ldsdst) {
  __builtin_amdgcn_global_load_lds(
      (const __attribute__((address_space(1))) unsigned int*)gsrc,
      (__attribute__((address_space(3))) unsigned int*)ldsdst, 16, 0, 0);
}

// ---------------- setup: fold/cast/repack weights (runs every launch) ----------------
// blocks 0..511   : wsw1f fragment-major [e][c(2)][ht(8)][ks(2)][lane(64)][e8(8)]
// blocks 512..575 : at_f  fragment-major [it(8)][ks(4)][lane(64)][e8(8)]
// blocks 576..607 : wct_f fragment-major [ht(8)][ks(2)][lane(64)][e8(8)]
// blocks 608..623 : bw[e][256..767] = W2e[e] copy
// blocks 624..631 : bw[e][0..255]   = b_sig@W1e[e] + b1e[e]
__global__ void setup_k(const float* __restrict__ A, const float* __restrict__ W_sig,
                        const float* __restrict__ b_sig, const float* __restrict__ W1e,
                        const float* __restrict__ b1e, const float* __restrict__ W2e,
                        const float* __restrict__ Wc,
                        unsigned short* __restrict__ wsw1f, unsigned short* __restrict__ at_f,
                        unsigned short* __restrict__ wct_f, float* __restrict__ bw) {
  int blk = blockIdx.x, tid = threadIdx.x;
  if (blk < 512) {                       // Wsw1[l][h] = sum_h1 W_sig[l,h1]*W1e[e,h1,h]
    int e = blk >> 6, l = blk & 63, h = tid;
    const float* w1 = W1e + e * 65536 + h;
    const float* ws = W_sig + l * 256;
    float acc = 0.f;
    #pragma unroll 8
    for (int h1 = 0; h1 < 256; ++h1) acc = fmaf(ws[h1], w1[h1 * 256], acc);
    int c = h >> 7, ht = (h >> 4) & 7, col = h & 15;
    int kks = l >> 5, lgl = (l >> 3) & 3, e8 = l & 7;
    int lane = lgl * 16 + col;
    wsw1f[((((e * 2 + c) * 8 + ht) * 2 + kks) * 64 + lane) * 8 + e8] = f2bf(acc);
  } else if (blk < 576) {                // at_f: value = A[j][i]
    int idx = (blk - 512) * 256 + tid;
    int frag = idx >> 3, e8 = idx & 7;
    int it = frag >> 8, ks = (frag >> 6) & 3, lane = frag & 63;
    int j = ks * 32 + (lane >> 4) * 8 + e8, i = it * 16 + (lane & 15);
    at_f[idx] = f2bf(A[j * 128 + i]);
  } else if (blk < 608) {                // wct_f: value = Wc[l][h']
    int idx = (blk - 576) * 256 + tid;
    int frag = idx >> 3, e8 = idx & 7;
    int ht = frag >> 7, ks = (frag >> 6) & 1, lane = frag & 63;
    int l = ks * 32 + (lane >> 4) * 8 + e8, h = ht * 16 + (lane & 15);
    wct_f[idx] = f2bf(Wc[l * 128 + h]);
  } else if (blk < 624) {                // bw W2 copy
    int idx = (blk - 608) * 256 + tid;   // 0..4095
    int e = idx >> 9, r = idx & 511;
    bw[e * 768 + 256 + r] = W2e[idx];
  } else {                               // bw bias fold
    int e = blk - 624, h = tid;
    const float* w1 = W1e + e * 65536 + h;
    float acc = b1e[e * 256 + h];
    for (int h1 = 0; h1 < 256; ++h1) acc = fmaf(b_sig[h1], w1[h1 * 256], acc);
    bw[e * 768 + h] = acc;
  }
}

// ---------------- main kernel ----------------
// LDS map (37888 B -> 4 blocks/CU):
//      0: Zt  [64 l][128 j] bf16 swzT(l)
//  16384: Zcb [128 d][64 l] bf16 swz8 -> M1buf [128 i][64 l] swz8 (wave-private band)
//  32768: bw: bias1 256f | W2 512f (async gload)
//  35840: s_cpart [4][128] f32
__global__ __launch_bounds__(256, 4) void dec_k(
    const float* __restrict__ zs, const float* __restrict__ zcr,
    const int* __restrict__ regime, const float* __restrict__ b2e,
    const float* __restrict__ bc, const float* __restrict__ Wo,
    const float* __restrict__ bo,
    const unsigned short* __restrict__ wsw1f, const unsigned short* __restrict__ at_f,
    const unsigned short* __restrict__ wct_f, const float* __restrict__ bw,
    float* __restrict__ out) {
  __shared__ __align__(16) char sm[37888];
  float* s_bias1 = (float*)(sm + 32768);
  float* s_W2    = s_bias1 + 256;
  float* s_cpart = (float*)(sm + 35840);

  const int bt = ((blockIdx.x & 7) << 8) | (blockIdx.x >> 3);  // XCD swizzle
  const int tid = threadIdx.x;
  const int lane = tid & 63, wave = tid >> 6, lg = lane >> 4, l15 = lane & 15;
  int e = regime[bt >> 6]; if (e >= 8) e = 0;
  const float b2_0 = b2e[2 * e], b2_1 = b2e[2 * e + 1], bo0 = bo[0];

  const float* Z  = zs  + (size_t)bt * 8192;
  const float* Zc = zcr + (size_t)bt * 8192;

  // ---- async gload bw (bias1|W2) -> LDS ----
  if (wave < 3)
    gload16((const char*)(bw + e * 768) + tid * 16, sm + 32768 + wave * 1024);

  // ---- P0: load Z/Zc, convert (cvt_pk), write LDS tiles ----
  float4 zcv[8];
  #pragma unroll
  for (int k = 0; k < 8; ++k) {
    int g = k * 256 + tid, d = g >> 4, l0 = (g & 15) * 4;
    zcv[k] = *(const float4*)(Zc + d * 64 + l0);
  }
  float4 z0v[4], z1v[4];
  #pragma unroll
  for (int k = 0; k < 4; ++k) {
    int g = k * 256 + tid, j = (g >> 4) * 2, l0 = (g & 15) * 4;
    const float* p = Z + j * 64 + l0;
    z0v[k] = *(const float4*)p;
    z1v[k] = *(const float4*)(p + 64);
  }
  // mc A-fragments (Wct, fragment-major coalesced)
  short8 wfr[2][2];
  #pragma unroll
  for (int m = 0; m < 2; ++m)
    #pragma unroll
    for (int ks = 0; ks < 2; ++ks)
      wfr[m][ks] = *(const short8*)(wct_f + ((((wave * 2 + m) * 2 + ks) * 64 + lane) << 3));

  #pragma unroll
  for (int k = 0; k < 8; ++k) {           // Zcb[d][l], swz8(d)
    int g = k * 256 + tid, d = g >> 4, l0 = (g & 15) * 4;
    unsigned lo = pkbf(zcv[k].x, zcv[k].y);
    unsigned hi = pkbf(zcv[k].z, zcv[k].w);
    int a = (d * 128 + l0 * 2) ^ ((d & 7) << 4);
    *(unsigned long long*)(sm + 16384 + a) = ((unsigned long long)hi << 32) | lo;
  }
  #pragma unroll
  for (int k = 0; k < 4; ++k) {           // Zt[l][j] transpose, swzT(l)
    int g = k * 256 + tid, j = (g >> 4) * 2, l0 = (g & 15) * 4;
    float a0[4] = {z0v[k].x, z0v[k].y, z0v[k].z, z0v[k].w};
    float a1[4] = {z1v[k].x, z1v[k].y, z1v[k].z, z1v[k].w};
    #pragma unroll
    for (int i2 = 0; i2 < 4; ++i2) {
      int l = l0 + i2;
      unsigned v = pkbf(a0[i2], a1[i2]);
      int a = (l * 256 + j * 2) ^ ((((l >> 2) ^ l) & 7) << 4);
      *(unsigned*)(sm + a) = v;
    }
  }
  __syncthreads();   // sync1: Zt/Zcb + bw ready

  // ---- m1 B-fragments (At, fragment-major) + mc epilogue consts ----
  short8 abfr[2][4];
  #pragma unroll
  for (int m = 0; m < 2; ++m)
    #pragma unroll
    for (int ks = 0; ks < 4; ++ks)
      abfr[m][ks] = *(const short8*)(at_f + ((((wave * 2 + m) * 4 + ks) * 64 + lane) << 3));
  float4 bcv[2], wov[2];
  #pragma unroll
  for (int m = 0; m < 2; ++m) {
    int hb = (wave * 2 + m) * 16 + lg * 4;
    bcv[m] = *(const float4*)(bc + hb);
    wov[m] = *(const float4*)(Wo + hb);
  }

  // ---- P1 mc: Hc = Wct(M=h') x Zcb(N=d) ----
  float cp[8];
  #pragma unroll
  for (int dt = 0; dt < 8; ++dt) cp[dt] = 0.f;
  #pragma unroll
  for (int dt = 0; dt < 8; ++dt) {
    int brow = dt * 16 + l15;
    short8 bfr0 = *(const short8*)(sm + 16384 + ((brow * 128 + lg * 16) ^ ((brow & 7) << 4)));
    short8 bfr1 = *(const short8*)(sm + 16384 + ((brow * 128 + lg * 16 + 64) ^ ((brow & 7) << 4)));
    #pragma unroll
    for (int m = 0; m < 2; ++m) {
      f32x4 acc = (f32x4){0.f, 0.f, 0.f, 0.f};
      acc = MFMA16(wfr[m][0], bfr0, acc);
      acc = MFMA16(wfr[m][1], bfr1, acc);
      #pragma unroll
      for (int r = 0; r < 4; ++r)
        cp[dt] += fmaxf(acc[r] + bcv[m][r], 0.f) * wov[m][r];
    }
  }
  #pragma unroll
  for (int dt = 0; dt < 8; ++dt) {
    cp[dt] += __shfl_xor(cp[dt], 16);
    cp[dt] += __shfl_xor(cp[dt], 32);
  }
  if (lane < 16) {
    #pragma unroll
    for (int dt = 0; dt < 8; ++dt)
      s_cpart[wave * 128 + dt * 16 + lane] = cp[dt];
  }

  // ---- issue Wsw1 chunk0 fragments (reg; consumed in P3-c0, hidden by P2) ----
  const unsigned short* wse = wsw1f + (size_t)e * 16384;
  short8 wsf0[8][2];
  #pragma unroll
  for (int ht = 0; ht < 8; ++ht)
    #pragma unroll
    for (int ks = 0; ks < 2; ++ks)
      wsf0[ht][ks] = *(const short8*)(wse + (((ht * 2 + ks) * 64 + lane) << 3));

  // ---- P2 m1: M1 = Zt(M=l) x At(N=i) ----
  f32x4 acc1[4][2];
  #pragma unroll
  for (int lt = 0; lt < 4; ++lt)
    #pragma unroll
    for (int m = 0; m < 2; ++m) acc1[lt][m] = (f32x4){0.f, 0.f, 0.f, 0.f};
  #pragma unroll
  for (int ks = 0; ks < 4; ++ks) {
    #pragma unroll
    for (int lt = 0; lt < 4; ++lt) {
      int arow = lt * 16 + l15;
      short8 afr = *(const short8*)(sm + ((arow * 256 + lg * 16 + ks * 64) ^
                                          ((((arow >> 2) ^ arow) & 7) << 4)));
      #pragma unroll
      for (int m = 0; m < 2; ++m) acc1[lt][m] = MFMA16(afr, abfr[m][ks], acc1[lt][m]);
    }
  }
  __syncthreads();   // sync2: Zcb/Zt reads retired; s_cpart visible

  // ---- issue Wsw1 chunk1 fragments (hidden by M1 write + P3-c0 compute) ----
  short8 wsf1[8][2];
  #pragma unroll
  for (int ht = 0; ht < 8; ++ht)
    #pragma unroll
    for (int ks = 0; ks < 2; ++ks)
      wsf1[ht][ks] = *(const short8*)(wse + 8192 + (((ht * 2 + ks) * 64 + lane) << 3));

  // ---- M1buf write (wave-private band) + own-band B-fragment read ----
  #pragma unroll
  for (int lt = 0; lt < 4; ++lt) {
    int l0 = lt * 16 + lg * 4;
    #pragma unroll
    for (int m = 0; m < 2; ++m) {
      int i = (wave * 2 + m) * 16 + l15;
      unsigned lo = pkbf(acc1[lt][m][0], acc1[lt][m][1]);
      unsigned hi = pkbf(acc1[lt][m][2], acc1[lt][m][3]);
      int a = (i * 128 + l0 * 2) ^ ((i & 7) << 4);
      *(unsigned long long*)(sm + 16384 + a) = ((unsigned long long)hi << 32) | lo;
    }
  }
  short8 mbfr[2][2];
  #pragma unroll
  for (int m = 0; m < 2; ++m) {
    int brow = (wave * 2 + m) * 16 + l15;
    #pragma unroll
    for (int ks = 0; ks < 2; ++ks)
      mbfr[m][ks] = *(const short8*)(sm + 16384 +
                       ((brow * 128 + lg * 16 + ks * 64) ^ ((brow & 7) << 4)));
  }

  // ---- P3: P = Wsw1(M=h, regs) x M1buf(N=d); @W2 fused in-lane ----
  float v0[2] = {0.f, 0.f}, v1[2] = {0.f, 0.f};
  #pragma unroll
  for (int c = 0; c < 2; ++c) {
    #pragma unroll
    for (int ht = 0; ht < 8; ++ht) {
      int h4 = c * 128 + ht * 16 + lg * 4;
      float4 b1v = *(const float4*)(s_bias1 + h4);
      float4 w2a = *(const float4*)(s_W2 + h4 * 2);
      float4 w2b = *(const float4*)(s_W2 + h4 * 2 + 4);
      #pragma unroll
      for (int m = 0; m < 2; ++m) {
        f32x4 acc = (f32x4){0.f, 0.f, 0.f, 0.f};
        if (c == 0) {
          acc = MFMA16(wsf0[ht][0], mbfr[m][0], acc);
          acc = MFMA16(wsf0[ht][1], mbfr[m][1], acc);
        } else {
          acc = MFMA16(wsf1[ht][0], mbfr[m][0], acc);
          acc = MFMA16(wsf1[ht][1], mbfr[m][1], acc);
        }
        float p0 = fmaxf(acc[0] + b1v.x, 0.f), p1 = fmaxf(acc[1] + b1v.y, 0.f);
        float p2 = fmaxf(acc[2] + b1v.z, 0.f), p3 = fmaxf(acc[3] + b1v.w, 0.f);
        v0[m] = fmaf(p0, w2a.x, fmaf(p1, w2a.z, fmaf(p2, w2b.x, fmaf(p3, w2b.z, v0[m]))));
        v1[m] = fmaf(p0, w2a.y, fmaf(p1, w2a.w, fmaf(p2, w2b.y, fmaf(p3, w2b.w, v1[m]))));
      }
    }
  }
  #pragma unroll
  for (int m = 0; m < 2; ++m) {
    v0[m] += __shfl_xor(v0[m], 16); v0[m] += __shfl_xor(v0[m], 32);
    v1[m] += __shfl_xor(v1[m], 16); v1[m] += __shfl_xor(v1[m], 32);
  }
  if (lane < 16) {
    #pragma unroll
    for (int m = 0; m < 2; ++m) {
      int d = (wave * 2 + m) * 16 + lane;
      float contrib = s_cpart[d] + s_cpart[128 + d] + s_cpart[256 + d] + s_cpart[384 + d];
      float mu = v0[m] + b2_0 + bo0 + contrib;
      float x = v1[m] + b2_1;
      float sg = fmaxf(x, 0.f) + log1pf(expf(-fabsf(x))) + 0.01f;
      out[(size_t)bt * 128 + d] = mu;
      out[262144 + (size_t)bt * 128 + d] = sg;
    }
  }
}

extern "C" void kernel_launch(void* const* d_in, const int* in_sizes, int n_in,
                              void* d_out, int out_size, void* d_ws, size_t ws_size,
                              hipStream_t stream) {
  const float* zs    = (const float*)d_in[0];
  const float* zcr   = (const float*)d_in[1];
  const float* A     = (const float*)d_in[2];
  const int*   reg   = (const int*)d_in[3];
  const float* W_sig = (const float*)d_in[4];
  const float* b_sig = (const float*)d_in[5];
  const float* W1e   = (const float*)d_in[6];
  const float* b1e   = (const float*)d_in[7];
  const float* W2e   = (const float*)d_in[8];
  const float* b2e   = (const float*)d_in[9];
  const float* Wc    = (const float*)d_in[10];
  const float* bcp   = (const float*)d_in[11];
  const float* Wo    = (const float*)d_in[12];
  const float* bo    = (const float*)d_in[13];

  unsigned short* wsw1f = (unsigned short*)d_ws;            // 131072 bf16 = 256 KB
  unsigned short* at_f  = wsw1f + 131072;                   // 16384 bf16 = 32 KB
  unsigned short* wct_f = at_f + 16384;                     // 8192 bf16  = 16 KB
  float* bw             = (float*)(wct_f + 8192);           // 8*768 f32  = 24 KB

  setup_k<<<632, 256, 0, stream>>>(A, W_sig, b_sig, W1e, b1e, W2e, Wc,
                                   wsw1f, at_f, wct_f, bw);
  dec_k<<<2048, 256, 0, stream>>>(zs, zcr, reg, b2e, bcp, Wo, bo,
                                  wsw1f, at_f, wct_f, bw, (float*)d_out);
}